// Round 1
// 947.011 us; speedup vs baseline: 1.0534x; 1.0534x over previous
//
#include <hip/hip_runtime.h>
#include <cstdint>
#include <cstddef>

#define B_ 2
#define L_ 2048
#define D_ 1024
#define H_ 16
#define DH_ 64

typedef unsigned short u16;
typedef __attribute__((ext_vector_type(8))) __bf16 bf16x8;
typedef __attribute__((ext_vector_type(8))) short short8;
typedef __attribute__((ext_vector_type(4))) float floatx4;
typedef __attribute__((ext_vector_type(4))) unsigned short ushort4v;

__device__ __forceinline__ u16 f2bf(float f) {
  union { float f; unsigned u; } v; v.f = f;
  return (u16)((v.u + 0x7FFFu + ((v.u >> 16) & 1u)) >> 16);
}

__device__ __forceinline__ floatx4 mfma16(bf16x8 a, bf16x8 b, floatx4 c) {
  return __builtin_amdgcn_mfma_f32_16x16x32_bf16(a, b, c, 0, 0, 0);
}

__device__ __forceinline__ bf16x8 ldfrag(const u16* p) {
  return *(const bf16x8*)(const void*)p;
}

__device__ __forceinline__ void gload_lds16(const void* g, void* l) {
  __builtin_amdgcn_global_load_lds(
      (__attribute__((address_space(1))) void*)g,
      (__attribute__((address_space(3))) void*)l, 16, 0, 0);
}

// ---------------- fp32 -> bf16 convert ----------------
__global__ void cvt_bf16_kernel(const float* __restrict__ in, u16* __restrict__ out, int n4) {
  int i = blockIdx.x * 256 + threadIdx.x;
  if (i >= n4) return;
  floatx4 v = ((const floatx4*)in)[i];
  ushort4v o;
#pragma unroll
  for (int j = 0; j < 4; j++) o[j] = f2bf(v[j]);
  ((ushort4v*)out)[i] = o;
}

// ---------------- bf16 GEMM, Y = A @ Bw^T (both K-contiguous) ----------------
// MODE 2: write fp32 row-major (M,N)  (only the out-projection uses this now)
template <int MODE>
__global__ __launch_bounds__(256) void gemm_bt(const u16* __restrict__ A,
                                               const u16* __restrict__ Bw,
                                               void* __restrict__ outv,
                                               int M, int N, int K) {
  __shared__ __align__(16) u16 As[128 * 32];
  __shared__ __align__(16) u16 Bs[128 * 32];
  const int t = threadIdx.x;
  const int lane = t & 63, w = t >> 6;
  const int wm = w >> 1, wn = w & 1;
  const int q = lane >> 4, c = lane & 15;
  const int nbn = N >> 7;
  const int bm = (int)blockIdx.x / nbn, bn = (int)blockIdx.x % nbn;
  const int m0 = bm << 7, n0 = bn << 7;
  const int rowS = t >> 2;        // 0..63
  const int colB = (t & 3) << 4;  // byte 0/16/32/48 within 64B row

  floatx4 acc[4][4];
#pragma unroll
  for (int i = 0; i < 4; i++)
#pragma unroll
    for (int j = 0; j < 4; j++) acc[i][j] = (floatx4){0.f, 0.f, 0.f, 0.f};

  for (int k0 = 0; k0 < K; k0 += 32) {
    __syncthreads();
#pragma unroll
    for (int ch = 0; ch < 2; ch++) {
      gload_lds16((const char*)(A + (size_t)(m0 + ch * 64 + rowS) * K + k0) + colB,
                  (char*)As + ch * 4096 + t * 16);
      gload_lds16((const char*)(Bw + (size_t)(n0 + ch * 64 + rowS) * K + k0) + colB,
                  (char*)Bs + ch * 4096 + t * 16);
    }
    __syncthreads();
    bf16x8 af[4], bfr[4];
#pragma unroll
    for (int mi = 0; mi < 4; mi++) af[mi] = ldfrag(As + (wm * 64 + mi * 16 + c) * 32 + q * 8);
#pragma unroll
    for (int ni = 0; ni < 4; ni++) bfr[ni] = ldfrag(Bs + (wn * 64 + ni * 16 + c) * 32 + q * 8);
#pragma unroll
    for (int mi = 0; mi < 4; mi++)
#pragma unroll
      for (int ni = 0; ni < 4; ni++)
        acc[mi][ni] = mfma16(af[mi], bfr[ni], acc[mi][ni]);
  }

#pragma unroll
  for (int mi = 0; mi < 4; mi++) {
#pragma unroll
    for (int ni = 0; ni < 4; ni++) {
      const int gnn = n0 + wn * 64 + ni * 16 + c;
#pragma unroll
      for (int r = 0; r < 4; r++) {
        const int gm = m0 + wm * 64 + mi * 16 + q * 4 + r;
        float val = acc[mi][ni][r];
        if (MODE == 2) {
          ((float*)outv)[(size_t)gm * N + gnn] = val;
        } else {
          const int b = gm >> 11, l = gm & 2047;
          const int h = gnn >> 6, dh = gnn & 63;
          if (MODE == 0)
            ((u16*)outv)[(((size_t)(b * H_ + h)) * L_ + l) * DH_ + dh] = f2bf(val);
          else
            ((u16*)outv)[(((size_t)(b * H_ + h)) * DH_ + dh) * L_ + l] = f2bf(val);
        }
      }
    }
  }
}

// ---------------- fused QKV projection: 3 GEMMs in one dispatch ----------------
// grid: (M/128) * 24 blocks. bnall 0..7 -> Q, 8..15 -> K, 16..23 -> V(transposed)
__global__ __launch_bounds__(256) void gemm_qkv(const u16* __restrict__ A,
                                                const u16* __restrict__ Wq,
                                                const u16* __restrict__ Wk,
                                                const u16* __restrict__ Wv,
                                                u16* __restrict__ Qh,
                                                u16* __restrict__ Kh,
                                                u16* __restrict__ Vt) {
  const int K = D_, N = D_;
  __shared__ __align__(16) u16 As[128 * 32];
  __shared__ __align__(16) u16 Bs[128 * 32];
  const int t = threadIdx.x;
  const int lane = t & 63, w = t >> 6;
  const int wm = w >> 1, wn = w & 1;
  const int q = lane >> 4, c = lane & 15;
  const int bid = (int)blockIdx.x;
  const int bm = bid / 24, bnall = bid % 24;
  const int which = bnall >> 3, bn = bnall & 7;
  const u16* Bw = (which == 0) ? Wq : ((which == 1) ? Wk : Wv);
  u16* outp = (which == 0) ? Qh : ((which == 1) ? Kh : Vt);
  const int m0 = bm << 7, n0 = bn << 7;
  const int rowS = t >> 2;
  const int colB = (t & 3) << 4;

  floatx4 acc[4][4];
#pragma unroll
  for (int i = 0; i < 4; i++)
#pragma unroll
    for (int j = 0; j < 4; j++) acc[i][j] = (floatx4){0.f, 0.f, 0.f, 0.f};

  for (int k0 = 0; k0 < K; k0 += 32) {
    __syncthreads();
#pragma unroll
    for (int ch = 0; ch < 2; ch++) {
      gload_lds16((const char*)(A + (size_t)(m0 + ch * 64 + rowS) * K + k0) + colB,
                  (char*)As + ch * 4096 + t * 16);
      gload_lds16((const char*)(Bw + (size_t)(n0 + ch * 64 + rowS) * K + k0) + colB,
                  (char*)Bs + ch * 4096 + t * 16);
    }
    __syncthreads();
    bf16x8 af[4], bfr[4];
#pragma unroll
    for (int mi = 0; mi < 4; mi++) af[mi] = ldfrag(As + (wm * 64 + mi * 16 + c) * 32 + q * 8);
#pragma unroll
    for (int ni = 0; ni < 4; ni++) bfr[ni] = ldfrag(Bs + (wn * 64 + ni * 16 + c) * 32 + q * 8);
#pragma unroll
    for (int mi = 0; mi < 4; mi++)
#pragma unroll
      for (int ni = 0; ni < 4; ni++)
        acc[mi][ni] = mfma16(af[mi], bfr[ni], acc[mi][ni]);
  }

#pragma unroll
  for (int mi = 0; mi < 4; mi++) {
#pragma unroll
    for (int ni = 0; ni < 4; ni++) {
      const int gnn = n0 + wn * 64 + ni * 16 + c;
#pragma unroll
      for (int r = 0; r < 4; r++) {
        const int gm = m0 + wm * 64 + mi * 16 + q * 4 + r;
        float val = acc[mi][ni][r];
        const int b = gm >> 11, l = gm & 2047;
        const int h = gnn >> 6, dh = gnn & 63;
        if (which < 2)
          outp[(((size_t)(b * H_ + h)) * L_ + l) * DH_ + dh] = f2bf(val);
        else
          outp[(((size_t)(b * H_ + h)) * DH_ + dh) * L_ + l] = f2bf(val);
      }
    }
  }
}

// ---------------- fused QK^T + softmax + PV ----------------
// grid: B*H*(L/16) blocks of 256 threads (4 waves).
// Block computes 16 score rows x 2048 cols; wave w owns cols [w*512, w*512+512).
// Scores live in registers. Writes normalized fp32 probs (kernel output) AND
// computes O = P @ V without re-reading P from HBM: each wave transposes its
// P chunk (16x32) through a per-wave LDS buffer into MFMA A-fragments, MFMAs
// against V^T fragments, then the 4 per-wave partial O tiles are reduced in LDS.
__global__ __launch_bounds__(256, 2) void attn_fused(const u16* __restrict__ Qh,
                                                     const u16* __restrict__ Kh,
                                                     const u16* __restrict__ Vt,
                                                     float* __restrict__ attn,
                                                     u16* __restrict__ concat) {
  const int t = threadIdx.x;
  const int lane = t & 63, w = t >> 6;
  const int q = lane >> 4, c = lane & 15;
  const int bh = (int)blockIdx.x >> 7;  // L/16 = 128 row-tiles per head
  const int mt = (int)blockIdx.x & 127;
  const int row0 = mt << 4;
  const int b = bh >> 4, h = bh & 15;
  const u16* Qp = Qh + (size_t)bh * L_ * DH_;
  const u16* Kp = Kh + (size_t)bh * L_ * DH_;
  const u16* Vp = Vt + (size_t)bh * DH_ * L_;
  float* Ap = attn + (size_t)bh * L_ * L_ + (size_t)row0 * L_;
  const int cbase = w << 9;

  __shared__ float redm[4][16];
  __shared__ float reds[4][16];
  // per-wave P staging: 16 rows x 32 keys bf16, row stride 40 u16 (80B, 16B
  // aligned, bank-spread) -> conflict-free ds_read_b128 A-fragments. x2 dbuf.
  __shared__ __align__(16) u16 Ps[4][2][16 * 40];
  // cross-wave O reduction, padded to 66 floats to kill q-group bank conflicts
  __shared__ float Ored[4][16][66];

  const bf16x8 aq0 = ldfrag(Qp + (row0 + c) * DH_ + q * 8);
  const bf16x8 aq1 = ldfrag(Qp + (row0 + c) * DH_ + 32 + q * 8);

  floatx4 S[32];
#pragma unroll
  for (int ct = 0; ct < 32; ct++) {
    const int n0 = cbase + (ct << 4);
    bf16x8 b0 = ldfrag(Kp + (n0 + c) * DH_ + q * 8);
    bf16x8 b1 = ldfrag(Kp + (n0 + c) * DH_ + 32 + q * 8);
    floatx4 a = (floatx4){0.f, 0.f, 0.f, 0.f};
    a = mfma16(aq0, b0, a);
    a = mfma16(aq1, b1, a);
    S[ct] = a * 0.125f;  // 1/sqrt(64)
  }

  // row max (rows handled by this lane: row0 + q*4 + r)
  float vmax[4] = {-1e30f, -1e30f, -1e30f, -1e30f};
#pragma unroll
  for (int ct = 0; ct < 32; ct++)
#pragma unroll
    for (int r = 0; r < 4; r++) vmax[r] = fmaxf(vmax[r], S[ct][r]);
#pragma unroll
  for (int m = 1; m < 16; m <<= 1)
#pragma unroll
    for (int r = 0; r < 4; r++) vmax[r] = fmaxf(vmax[r], __shfl_xor(vmax[r], m, 64));

  if (c == 0) {
#pragma unroll
    for (int r = 0; r < 4; r++) redm[w][q * 4 + r] = vmax[r];
  }
  __syncthreads();
  float rmax[4];
#pragma unroll
  for (int r = 0; r < 4; r++)
    rmax[r] = fmaxf(fmaxf(redm[0][q * 4 + r], redm[1][q * 4 + r]),
                    fmaxf(redm[2][q * 4 + r], redm[3][q * 4 + r]));

  // exp + row sum
  float vsum[4] = {0.f, 0.f, 0.f, 0.f};
#pragma unroll
  for (int ct = 0; ct < 32; ct++)
#pragma unroll
    for (int r = 0; r < 4; r++) {
      float e = __expf(S[ct][r] - rmax[r]);
      S[ct][r] = e;
      vsum[r] += e;
    }
#pragma unroll
  for (int m = 1; m < 16; m <<= 1)
#pragma unroll
    for (int r = 0; r < 4; r++) vsum[r] += __shfl_xor(vsum[r], m, 64);
  if (c == 0) {
#pragma unroll
    for (int r = 0; r < 4; r++) reds[w][q * 4 + r] = vsum[r];
  }
  __syncthreads();
  float inv[4];
#pragma unroll
  for (int r = 0; r < 4; r++)
    inv[r] = 1.0f / (reds[0][q * 4 + r] + reds[1][q * 4 + r] +
                     reds[2][q * 4 + r] + reds[3][q * 4 + r]);

  // normalize in-register, then write fp32 probs (stores drain async under PV)
#pragma unroll
  for (int ct = 0; ct < 32; ct++)
#pragma unroll
    for (int r = 0; r < 4; r++) S[ct][r] *= inv[r];

#pragma unroll
  for (int ct = 0; ct < 32; ct++) {
    const int n0 = cbase + (ct << 4);
#pragma unroll
    for (int r = 0; r < 4; r++)
      Ap[(size_t)(q * 4 + r) * L_ + n0 + c] = S[ct][r];
  }

  // ---- PV: O_partial[16x64] over this wave's 512 keys ----
  floatx4 oacc[4];
#pragma unroll
  for (int nt = 0; nt < 4; nt++) oacc[nt] = (floatx4){0.f, 0.f, 0.f, 0.f};

#pragma unroll
  for (int cp = 0; cp < 16; cp++) {
    u16* Pb = Ps[w][cp & 1];
    // stage 16x32 chunk: lane holds rows q*4+r, key col (2*cp+dd)*16 + c
#pragma unroll
    for (int dd = 0; dd < 2; dd++)
#pragma unroll
      for (int r = 0; r < 4; r++)
        Pb[(q * 4 + r) * 40 + dd * 16 + c] = f2bf(S[2 * cp + dd][r]);
    // A-fragment: row = c, k = q*8..q*8+7 (same-wave DS ops are in-order)
    bf16x8 a = ldfrag(Pb + c * 40 + q * 8);
    const int key0 = cbase + cp * 32;
#pragma unroll
    for (int nt = 0; nt < 4; nt++) {
      bf16x8 bfr = ldfrag(Vp + (size_t)(nt * 16 + c) * L_ + key0 + q * 8);
      oacc[nt] = mfma16(a, bfr, oacc[nt]);
    }
  }

  // cross-wave reduction of the 4 partial O tiles
#pragma unroll
  for (int nt = 0; nt < 4; nt++)
#pragma unroll
    for (int r = 0; r < 4; r++)
      Ored[w][q * 4 + r][nt * 16 + c] = oacc[nt][r];
  __syncthreads();

  const int row = t >> 4;          // 0..15
  const int dh0 = (t & 15) << 2;   // 0,4,...,60
  float s0 = 0.f, s1 = 0.f, s2 = 0.f, s3 = 0.f;
#pragma unroll
  for (int ww = 0; ww < 4; ww++) {
    s0 += Ored[ww][row][dh0 + 0];
    s1 += Ored[ww][row][dh0 + 1];
    s2 += Ored[ww][row][dh0 + 2];
    s3 += Ored[ww][row][dh0 + 3];
  }
  ushort4v o;
  o[0] = f2bf(s0); o[1] = f2bf(s1); o[2] = f2bf(s2); o[3] = f2bf(s3);
  *(ushort4v*)&concat[((size_t)(b * L_ + row0 + row)) * D_ + h * DH_ + dh0] = o;
}

// ---------------- launch ----------------
extern "C" void kernel_launch(void* const* d_in, const int* in_sizes, int n_in,
                              void* d_out, int out_size, void* d_ws, size_t ws_size,
                              hipStream_t stream) {
  const float* x = (const float*)d_in[0];
  const float* Wq = (const float*)d_in[1];
  const float* Wk = (const float*)d_in[2];
  const float* Wv = (const float*)d_in[3];
  const float* Wo = (const float*)d_in[4];
  float* out = (float*)d_out;

  char* ws = (char*)d_ws;
  u16* xb = (u16*)(ws + 0);              //  8 MB  (B*L*D bf16)
  u16* wqb = (u16*)(ws + 8388608);       //  2 MB
  u16* wkb = (u16*)(ws + 10485760);      //  2 MB
  u16* wvb = (u16*)(ws + 12582912);      //  2 MB
  u16* wob = (u16*)(ws + 14680064);      //  2 MB
  u16* Qh = (u16*)(ws + 16777216);       //  8 MB  (B,H,L,DH)
  u16* Kh = (u16*)(ws + 25165824);       //  8 MB
  u16* Vt = (u16*)(ws + 33554432);       //  8 MB  (B,H,DH,L)
  u16* concat = (u16*)(ws + 41943040);   //  8 MB  (B,L,D)
  // total 48 MB

  const int MK = B_ * L_ * D_;  // 4194304
  const int WK = D_ * D_;       // 1048576
  cvt_bf16_kernel<<<MK / 4 / 256, 256, 0, stream>>>(x, xb, MK / 4);
  cvt_bf16_kernel<<<WK / 4 / 256, 256, 0, stream>>>(Wq, wqb, WK / 4);
  cvt_bf16_kernel<<<WK / 4 / 256, 256, 0, stream>>>(Wk, wkb, WK / 4);
  cvt_bf16_kernel<<<WK / 4 / 256, 256, 0, stream>>>(Wv, wvb, WK / 4);
  cvt_bf16_kernel<<<WK / 4 / 256, 256, 0, stream>>>(Wo, wob, WK / 4);

  const int M = B_ * L_, N = D_, K = D_;

  // fused Q/K/V projections: 32*24 = 768 blocks (~3 blocks/CU in flight)
  gemm_qkv<<<(M / 128) * 24, 256, 0, stream>>>(xb, wqb, wkb, wvb, Qh, Kh, Vt);

  float* attn = out + (size_t)B_ * L_ * D_;  // offset 4194304 floats
  attn_fused<<<B_ * H_ * (L_ / 16), 256, 0, stream>>>(Qh, Kh, Vt, attn, concat);

  gemm_bt<2><<<(M / 128) * (N / 128), 256, 0, stream>>>(concat, wob, (void*)out, M, N, K);
}